// Round 7
// baseline (180.296 us; speedup 1.0000x reference)
//
#include <hip/hip_runtime.h>

#define ALPHA_C 0.9f
#define EPS_C 1e-3f

typedef unsigned short u16;
typedef __attribute__((ext_vector_type(8))) short short8;
typedef __attribute__((ext_vector_type(4))) short short4v;
typedef __attribute__((ext_vector_type(4))) float f32x4;
#define MFMA(a, b, c) __builtin_amdgcn_mfma_f32_16x16x32_bf16(a, b, c, 0, 0, 0)
// compiler-only ordering fence; wave-private LDS hazards are in-order in HW
#define LDS_FENCE() asm volatile("" ::: "memory")
// raw barriers: do NOT drain vmcnt (in-flight global loads/stores survive)
#define BAR_TOP()    { LDS_FENCE(); __builtin_amdgcn_s_barrier(); LDS_FENCE(); }
#define BAR_STAGED() { LDS_FENCE(); asm volatile("s_waitcnt lgkmcnt(0)" ::: "memory"); \
                       __builtin_amdgcn_s_barrier(); LDS_FENCE(); }

__device__ __forceinline__ u16 f2bf(float f) {
  union { float f; unsigned u; } v; v.f = f;
  unsigned u = v.u;
  u += 0x7FFFu + ((u >> 16) & 1u);
  return (u16)(u >> 16);
}
__device__ __forceinline__ float bf2f(u16 h) {
  union { unsigned u; float f; } v; v.u = ((unsigned)h) << 16;
  return v.f;
}

// ---------------------------------------------------------------------------
// K0: weight conversion fp32 -> bf16, packed in MFMA B-fragment order.
__global__ __launch_bounds__(256) void k_conv(
    const float* __restrict__ W1, const float* __restrict__ W2, const float* __restrict__ W3,
    const float* __restrict__ V1, const float* __restrict__ V2,
    u16* __restrict__ PW1T, u16* __restrict__ PW1n, u16* __restrict__ PV1T, u16* __restrict__ PV1n,
    u16* __restrict__ PW3T, u16* __restrict__ PW3n, u16* __restrict__ PW2T, u16* __restrict__ PW2n,
    u16* __restrict__ PV2T, u16* __restrict__ PV2n, float* __restrict__ DP) {
  int i = blockIdx.x * 256 + threadIdx.x;   // 0..32767
  if (i < 256) DP[i] = 0.f;
  {
    int k = i >> 6, j = i & 63;             // W1[k][j], V1[k][j]  (512x64)
    u16 b = f2bf(W1[i]);
    PW1T[((((j >> 4) * 16 + (k >> 5)) * 4 + ((k & 31) >> 3)) * 16 + (j & 15)) * 8 + (k & 7)] = b;
    PW1n[((((k >> 4) * 2 + (j >> 5)) * 4 + ((j & 31) >> 3)) * 16 + (k & 15)) * 8 + (j & 7)] = b;
    u16 c = f2bf(V1[i]);
    PV1T[((((j >> 4) * 16 + (k >> 5)) * 4 + ((k & 31) >> 3)) * 16 + (j & 15)) * 8 + (k & 7)] = c;
    PV1n[((((k >> 4) * 2 + (j >> 5)) * 4 + ((j & 31) >> 3)) * 16 + (k & 15)) * 8 + (j & 7)] = c;
  }
  {
    int k = i >> 9, n = i & 511;            // W3[k][n] (64x512)
    u16 b = f2bf(W3[i]);
    PW3T[((((n >> 4) * 2 + (k >> 5)) * 4 + ((k & 31) >> 3)) * 16 + (n & 15)) * 8 + (k & 7)] = b;
    PW3n[((((k >> 4) * 16 + (n >> 5)) * 4 + ((n & 31) >> 3)) * 16 + (k & 15)) * 8 + (n & 7)] = b;
  }
  if (i < 4096) {
    int k = i >> 6, j = i & 63;             // W2[k][j], V2[k][j] (64x64)
    u16 b = f2bf(W2[i]);
    PW2T[((((j >> 4) * 2 + (k >> 5)) * 4 + ((k & 31) >> 3)) * 16 + (j & 15)) * 8 + (k & 7)] = b;
    PW2n[((((k >> 4) * 2 + (j >> 5)) * 4 + ((j & 31) >> 3)) * 16 + (k & 15)) * 8 + (j & 7)] = b;
    u16 c = f2bf(V2[i]);
    PV2T[((((j >> 4) * 2 + (k >> 5)) * 4 + ((k & 31) >> 3)) * 16 + (j & 15)) * 8 + (k & 7)] = c;
    PV2n[((((k >> 4) * 2 + (j >> 5)) * 4 + ((j & 31) >> 3)) * 16 + (k & 15)) * 8 + (j & 7)] = c;
  }
}

// helper: load 8 b-fragments from global (frag index expression in j) - used by k_out
#define LDG8(dst, P, FRAG)                                                      \
  _Pragma("unroll") for (int j = 0; j < 8; ++j)                                 \
    dst[j] = *(const short8*)&P[((size_t)(FRAG) * 64 + lane) * 8];

// stage 16 contiguous fragments (16KB) into Ws at local frag base DST
#define STAGE16(DST, P, SRCFRAG)                                                \
  _Pragma("unroll") for (int c = 0; c < 4; ++c)                                 \
    *(short8*)&Ws[((DST) * 512) + (c * 256 + tid) * 8] =                        \
      *(const short8*)&P[((size_t)(SRCFRAG) * 512) + (c * 256 + tid) * 8];

// stage 4 chunks of 4 fragments: chunk t from global frag (t*16 + OFF) to local (DST + t*4)
#define STAGE4x4(DST, P, OFF)                                                   \
  _Pragma("unroll") for (int t = 0; t < 4; ++t)                                 \
    *(short8*)&Ws[((DST) + t * 4) * 512 + tid * 8] =                            \
      *(const short8*)&P[((size_t)(t * 16 + (OFF))) * 512 + tid * 8];

// ---------------------------------------------------------------------------
__global__ __launch_bounds__(256, 2) void k_fused(
    const float* __restrict__ x,
    const u16* __restrict__ PW1T, const float* __restrict__ b1,
    const u16* __restrict__ PW2T, const float* __restrict__ b2,
    const u16* __restrict__ PW3T, const float* __restrict__ b3,
    const u16* __restrict__ PV1T, const float* __restrict__ c1,
    const u16* __restrict__ PV2T, const u16* __restrict__ PV2n, const float* __restrict__ c2,
    const float* __restrict__ V3, const float* __restrict__ c3,
    const u16* __restrict__ PV1n, const u16* __restrict__ PW3n,
    const u16* __restrict__ PW2n, const u16* __restrict__ PW1n,
    u16* __restrict__ FP, u16* __restrict__ T2P, u16* __restrict__ GVB,
    float* __restrict__ NUM, float* __restrict__ DP) {
  __shared__ __align__(16) u16 H1s[64 * 72];
  __shared__ __align__(16) u16 H2s[64 * 72];
  __shared__ __align__(16) u16 S2s[64 * 72];
  __shared__ __align__(16) u16 As[64 * 136];
  __shared__ __align__(16) u16 Ws[16384];    // 32 KB shared weight window
  __shared__ float dred[4];
  const int tid = threadIdx.x;
  const int lane = tid & 63, w = tid >> 6, q = lane >> 4, r = lane & 15;
  const int m0 = blockIdx.x * 64;
  const int arow = w * 16 + r;
  const int strip = blockIdx.x * 4 + w;
  const int h = lane >> 5, c4 = lane & 31;
  const float* xbase = x + (size_t)(m0 + w * 16) * 512;

  // ================= phase A1: H1 = relu(x @ W1 + b1) =================
  f32x4 acc1[4] = {};
  float4 xr[8];
  #pragma unroll
  for (int it = 0; it < 8; ++it)
    xr[it] = *(const float4*)&xbase[(it * 2 + h) * 512 + c4 * 4];
  #pragma unroll 1
  for (int kc = 0; kc < 4; ++kc) {
    BAR_TOP();
    STAGE4x4(0, PW1T, kc * 4);
    #pragma unroll
    for (int it = 0; it < 8; ++it) {
      float4 v = xr[it]; short4v s4;
      s4[0] = (short)f2bf(v.x); s4[1] = (short)f2bf(v.y);
      s4[2] = (short)f2bf(v.z); s4[3] = (short)f2bf(v.w);
      *(short4v*)&As[(w * 16 + it * 2 + h) * 136 + c4 * 4] = s4;
    }
    if (kc < 3) {
      #pragma unroll
      for (int it = 0; it < 8; ++it)
        xr[it] = *(const float4*)&xbase[(it * 2 + h) * 512 + (kc + 1) * 128 + c4 * 4];
    }
    BAR_STAGED();
    #pragma unroll
    for (int ks = 0; ks < 4; ++ks) {
      short8 a = *(const short8*)&As[arow * 136 + ks * 32 + q * 8];
      #pragma unroll
      for (int t = 0; t < 4; ++t) {
        short8 b = *(const short8*)&Ws[((t * 4 + ks) * 64 + lane) * 8];
        acc1[t] = MFMA(a, b, acc1[t]);
      }
    }
  }
  #pragma unroll
  for (int t = 0; t < 4; ++t) {
    int col = t * 16 + r; float bv = b1[col];
    #pragma unroll
    for (int g = 0; g < 4; ++g) {
      float hh = acc1[t][g] + bv; hh = hh > 0.f ? hh : 0.f;
      H1s[(w * 16 + q * 4 + g) * 72 + col] = f2bf(hh);
    }
  }
  LDS_FENCE();

  // ================= phase A2: H2 = relu(H1 @ W2 + b2)  [direct, 8 KB] =================
  {
    short8 a0 = *(const short8*)&H1s[arow * 72 + 0 + q * 8];
    short8 a1 = *(const short8*)&H1s[arow * 72 + 32 + q * 8];
    f32x4 acc2[4] = {};
    #pragma unroll
    for (int t = 0; t < 4; ++t) {
      short8 b0 = *(const short8*)&PW2T[((t * 2 + 0) * 64 + lane) * 8];
      short8 b1 = *(const short8*)&PW2T[((t * 2 + 1) * 64 + lane) * 8];
      acc2[t] = MFMA(a0, b0, acc2[t]);
      acc2[t] = MFMA(a1, b1, acc2[t]);
    }
    #pragma unroll
    for (int t = 0; t < 4; ++t) {
      int col = t * 16 + r; float bv = b2[col];
      #pragma unroll
      for (int g = 0; g < 4; ++g) {
        float hh = acc2[t][g] + bv; hh = hh > 0.f ? hh : 0.f;
        H2s[(w * 16 + q * 4 + g) * 72 + col] = f2bf(hh);
      }
    }
  }
  LDS_FENCE();

  // ================= phase B: F = H2 @ W3 + b3; G1 accum = F @ V1 =================
  f32x4 g1acc[4] = {};
  float ssq[4] = {0.f, 0.f, 0.f, 0.f};
  short8 h2a0 = *(const short8*)&H2s[arow * 72 + 0 + q * 8];
  short8 h2a1 = *(const short8*)&H2s[arow * 72 + 32 + q * 8];
  #pragma unroll 1
  for (int nc = 0; nc < 4; ++nc) {
    BAR_TOP();
    STAGE16(0, PW3T, nc * 16);
    STAGE4x4(16, PV1T, nc * 4);
    BAR_STAGED();
    f32x4 facc[8] = {};
    #pragma unroll
    for (int t = 0; t < 8; ++t) {
      short8 b0 = *(const short8*)&Ws[((t * 2 + 0) * 64 + lane) * 8];
      short8 b1 = *(const short8*)&Ws[((t * 2 + 1) * 64 + lane) * 8];
      facc[t] = MFMA(h2a0, b0, facc[t]);
      facc[t] = MFMA(h2a1, b1, facc[t]);
    }
    #pragma unroll
    for (int t = 0; t < 8; ++t) {
      float bv = b3[nc * 128 + t * 16 + r];
      short4v s4;
      #pragma unroll
      for (int g = 0; g < 4; ++g) {
        float v = facc[t][g] + bv;
        ssq[g] += v * v;
        u16 bb = f2bf(v);
        As[(w * 16 + q * 4 + g) * 136 + t * 16 + r] = bb;
        s4[g] = (short)bb;
      }
      *(short4v*)&FP[(size_t)(((strip * 4 + nc) * 8 + t) * 64 + lane) * 4] = s4;
    }
    LDS_FENCE();
    #pragma unroll
    for (int ks = 0; ks < 4; ++ks) {
      short8 a = *(const short8*)&As[arow * 136 + ks * 32 + q * 8];
      #pragma unroll
      for (int t = 0; t < 4; ++t) {
        short8 b = *(const short8*)&Ws[((16 + t * 4 + ks) * 64 + lane) * 8];
        g1acc[t] = MFMA(a, b, g1acc[t]);
      }
    }
  }

  // G1 = relu(g1acc + c1) -> S2s
  f32x4 g1v[4];
  #pragma unroll
  for (int t = 0; t < 4; ++t) {
    int col = t * 16 + r; float cv = c1[col];
    #pragma unroll
    for (int g = 0; g < 4; ++g) {
      float v = g1acc[t][g] + cv; v = v > 0.f ? v : 0.f;
      g1v[t][g] = v;
      S2s[(w * 16 + q * 4 + g) * 72 + col] = f2bf(v);
    }
  }
  LDS_FENCE();
  // g2 = G1 @ V2T  [direct, 8 KB]
  f32x4 g2acc[4] = {};
  {
    short8 a0 = *(const short8*)&S2s[arow * 72 + 0 + q * 8];
    short8 a1 = *(const short8*)&S2s[arow * 72 + 32 + q * 8];
    #pragma unroll
    for (int t = 0; t < 4; ++t) {
      short8 b0 = *(const short8*)&PV2T[((t * 2 + 0) * 64 + lane) * 8];
      short8 b1 = *(const short8*)&PV2T[((t * 2 + 1) * 64 + lane) * 8];
      g2acc[t] = MFMA(a0, b0, g2acc[t]);
      g2acc[t] = MFMA(a1, b1, g2acc[t]);
    }
  }
  // s3 = (g2pre>0)*V3 -> S2s; lyap partial
  float tot[4] = {0.f, 0.f, 0.f, 0.f};
  #pragma unroll
  for (int t = 0; t < 4; ++t) {
    int col = t * 16 + r;
    float c2v = c2[col], v3v = V3[col];
    #pragma unroll
    for (int g = 0; g < 4; ++g) {
      float pre = g2acc[t][g] + c2v;
      float g2 = pre > 0.f ? pre : 0.f;
      S2s[(w * 16 + q * 4 + g) * 72 + col] = pre > 0.f ? f2bf(v3v) : (u16)0;
      tot[g] += g2 * v3v;
    }
  }
  LDS_FENCE();
  // s2 = s3 @ V2 (natural), masked by G1>0 -> S2s  [direct, 8 KB]
  f32x4 s2acc[4] = {};
  {
    short8 a0 = *(const short8*)&S2s[arow * 72 + 0 + q * 8];
    short8 a1 = *(const short8*)&S2s[arow * 72 + 32 + q * 8];
    #pragma unroll
    for (int t = 0; t < 4; ++t) {
      short8 b0 = *(const short8*)&PV2n[((t * 2 + 0) * 64 + lane) * 8];
      short8 b1 = *(const short8*)&PV2n[((t * 2 + 1) * 64 + lane) * 8];
      s2acc[t] = MFMA(a0, b0, s2acc[t]);
      s2acc[t] = MFMA(a1, b1, s2acc[t]);
    }
  }
  #pragma unroll
  for (int t = 0; t < 4; ++t) {
    int col = t * 16 + r;
    #pragma unroll
    for (int g = 0; g < 4; ++g) {
      float sv = g1v[t][g] > 0.f ? s2acc[t][g] : 0.f;
      S2s[(w * 16 + q * 4 + g) * 72 + col] = f2bf(sv);
    }
  }
  LDS_FENCE();
  float c3v = c3[0];
  float lyap_row[4];
  #pragma unroll
  for (int g = 0; g < 4; ++g) {
    float s = tot[g] + EPS_C * ssq[g];
    s += __shfl_xor(s, 1); s += __shfl_xor(s, 2); s += __shfl_xor(s, 4); s += __shfl_xor(s, 8);
    lyap_row[g] = s + c3v;
  }

  // all FP stores must land before same-address re-reads in phase C
  asm volatile("s_waitcnt vmcnt(0)" ::: "memory");

  // ================= phase C: U = s2 @ V1^T + 2eps*F; T3 accum = U @ W3^T =================
  f32x4 t3acc[4] = {};
  short8 s2a0 = *(const short8*)&S2s[arow * 72 + 0 + q * 8];
  short8 s2a1 = *(const short8*)&S2s[arow * 72 + 32 + q * 8];
  #pragma unroll 1
  for (int nc = 0; nc < 4; ++nc) {
    BAR_TOP();
    STAGE16(0, PV1n, nc * 16);
    STAGE4x4(16, PW3n, nc * 4);
    BAR_STAGED();
    short4v fpr[8];
    #pragma unroll
    for (int t = 0; t < 8; ++t)
      fpr[t] = *(const short4v*)&FP[(size_t)(((strip * 4 + nc) * 8 + t) * 64 + lane) * 4];
    f32x4 uacc[8] = {};
    #pragma unroll
    for (int t = 0; t < 8; ++t) {
      short8 b0 = *(const short8*)&Ws[((t * 2 + 0) * 64 + lane) * 8];
      short8 b1 = *(const short8*)&Ws[((t * 2 + 1) * 64 + lane) * 8];
      uacc[t] = MFMA(s2a0, b0, uacc[t]);
      uacc[t] = MFMA(s2a1, b1, uacc[t]);
    }
    #pragma unroll
    for (int t = 0; t < 8; ++t) {
      #pragma unroll
      for (int g = 0; g < 4; ++g) {
        As[(w * 16 + q * 4 + g) * 136 + t * 16 + r] =
            f2bf(uacc[t][g] + 2.f * EPS_C * bf2f((u16)fpr[t][g]));
      }
    }
    LDS_FENCE();
    #pragma unroll
    for (int ks = 0; ks < 4; ++ks) {
      short8 a = *(const short8*)&As[arow * 136 + ks * 32 + q * 8];
      #pragma unroll
      for (int t = 0; t < 4; ++t) {
        short8 b = *(const short8*)&Ws[((16 + t * 4 + ks) * 64 + lane) * 8];
        t3acc[t] = MFMA(a, b, t3acc[t]);
      }
    }
  }
  // T3 masked by H2>0 -> H2s
  #pragma unroll
  for (int t = 0; t < 4; ++t) {
    int col = t * 16 + r;
    #pragma unroll
    for (int g = 0; g < 4; ++g) {
      int addr = (w * 16 + q * 4 + g) * 72 + col;
      u16 h2 = H2s[addr];
      H2s[addr] = h2 ? f2bf(t3acc[t][g]) : (u16)0;
    }
  }
  LDS_FENCE();
  // T2 = T3 @ W2 (natural), masked by H1>0 -> H1s  [direct, 8 KB]
  f32x4 t2acc[4] = {};
  {
    short8 a0 = *(const short8*)&H2s[arow * 72 + 0 + q * 8];
    short8 a1 = *(const short8*)&H2s[arow * 72 + 32 + q * 8];
    #pragma unroll
    for (int t = 0; t < 4; ++t) {
      short8 b0 = *(const short8*)&PW2n[((t * 2 + 0) * 64 + lane) * 8];
      short8 b1 = *(const short8*)&PW2n[((t * 2 + 1) * 64 + lane) * 8];
      t2acc[t] = MFMA(a0, b0, t2acc[t]);
      t2acc[t] = MFMA(a1, b1, t2acc[t]);
    }
  }
  #pragma unroll
  for (int t = 0; t < 4; ++t) {
    int col = t * 16 + r;
    #pragma unroll
    for (int g = 0; g < 4; ++g) {
      int addr = (w * 16 + q * 4 + g) * 72 + col;
      u16 h1 = H1s[addr];
      H1s[addr] = h1 ? f2bf(t2acc[t][g]) : (u16)0;
    }
  }
  LDS_FENCE();
  // T2 A-fragments -> packed global (coalesced), reused for GV
  short8 v0 = *(const short8*)&H1s[arow * 72 + 0 + q * 8];
  short8 v1 = *(const short8*)&H1s[arow * 72 + 32 + q * 8];
  *(short8*)&T2P[(size_t)((strip * 2 + 0) * 64 + lane) * 8] = v0;
  *(short8*)&T2P[(size_t)((strip * 2 + 1) * 64 + lane) * 8] = v1;
  // GV = T2 @ W1^T: row norms + (optionally) packed bf16 GV store
  float ssq2[4] = {0.f, 0.f, 0.f, 0.f};
  #pragma unroll 1
  for (int nc = 0; nc < 4; ++nc) {
    BAR_TOP();
    STAGE16(0, PW1n, nc * 16);
    BAR_STAGED();
    f32x4 acc[8] = {};
    #pragma unroll
    for (int t = 0; t < 8; ++t) {
      short8 b0 = *(const short8*)&Ws[((t * 2 + 0) * 64 + lane) * 8];
      short8 b1 = *(const short8*)&Ws[((t * 2 + 1) * 64 + lane) * 8];
      acc[t] = MFMA(v0, b0, acc[t]);
      acc[t] = MFMA(v1, b1, acc[t]);
    }
    if (GVB != nullptr) {
      #pragma unroll
      for (int t = 0; t < 8; ++t) {
        short4v s4;
        #pragma unroll
        for (int g = 0; g < 4; ++g) {
          float v = acc[t][g];
          ssq2[g] += v * v;
          s4[g] = (short)f2bf(v);
        }
        *(short4v*)&GVB[(size_t)(((strip * 4 + nc) * 8 + t) * 64 + lane) * 4] = s4;
      }
    } else {
      #pragma unroll
      for (int t = 0; t < 8; ++t)
        #pragma unroll
        for (int g = 0; g < 4; ++g) ssq2[g] += acc[t][g] * acc[t][g];
    }
  }
  float totw = 0.f;
  #pragma unroll
  for (int g = 0; g < 4; ++g) {
    float s = ssq2[g];
    s += __shfl_xor(s, 1); s += __shfl_xor(s, 2); s += __shfl_xor(s, 4); s += __shfl_xor(s, 8);
    if (r == 0) {
      int rowg = m0 + w * 16 + q * 4 + g;
      float nm = s + ALPHA_C * lyap_row[g];
      NUM[rowg] = nm > 0.f ? nm : 0.f;
    }
    s += __shfl_xor(s, 16); s += __shfl_xor(s, 32);
    totw += s;
  }
  if (lane == 0) dred[w] = totw;
  __syncthreads();
  if (tid == 0) atomicAdd(&DP[blockIdx.x & 255], dred[0] + dred[1] + dred[2] + dred[3]);
}

// ---------------------------------------------------------------------------
// K2a (fallback): recompute GV from packed T2 via MFMA; out = F - (num/denom)*GV.
__global__ __launch_bounds__(256, 2) void k_out(
    const u16* __restrict__ T2P, const u16* __restrict__ PW1n,
    const u16* __restrict__ FP, const float* __restrict__ NUM, const float* __restrict__ DP,
    float* __restrict__ out) {
  __shared__ float red[256];
  __shared__ __align__(16) float OutS[64 * 132];
  const int tid = threadIdx.x;
  const int lane = tid & 63, w = tid >> 6, q = lane >> 4, r = lane & 15;
  const int m0 = blockIdx.x * 64;
  const int strip = blockIdx.x * 4 + w;
  red[tid] = DP[tid];
  __syncthreads();
  for (int s = 128; s >= 1; s >>= 1) {
    if (tid < s) red[tid] += red[tid + s];
    __syncthreads();
  }
  const float inv_denom = 1.f / red[0];
  float sc[4];
  #pragma unroll
  for (int g = 0; g < 4; ++g) sc[g] = NUM[m0 + w * 16 + q * 4 + g] * inv_denom;
  short8 a0 = *(const short8*)&T2P[(size_t)((strip * 2 + 0) * 64 + lane) * 8];
  short8 a1 = *(const short8*)&T2P[(size_t)((strip * 2 + 1) * 64 + lane) * 8];
  short8 bA[8], bB[8];
  LDG8(bA, PW1n, ((j >> 1) * 2 + (j & 1)));                      // nc0 t0-3
  #pragma unroll 1
  for (int nc = 0; nc < 4; ++nc) {
    LDG8(bB, PW1n, ((nc * 8 + 4 + (j >> 1)) * 2 + (j & 1)));     // t4-7
    short4v fpr[8];
    #pragma unroll
    for (int t = 0; t < 8; ++t)
      fpr[t] = *(const short4v*)&FP[(size_t)(((strip * 4 + nc) * 8 + t) * 64 + lane) * 4];
    f32x4 acc[8] = {};
    #pragma unroll
    for (int t = 0; t < 4; ++t) {
      acc[t] = MFMA(a0, bA[t * 2 + 0], acc[t]);
      acc[t] = MFMA(a1, bA[t * 2 + 1], acc[t]);
    }
    int ncn = (nc + 1) & 3;
    LDG8(bA, PW1n, ((ncn * 8 + (j >> 1)) * 2 + (j & 1)));        // next t0-3
    #pragma unroll
    for (int t = 0; t < 4; ++t) {
      acc[4 + t] = MFMA(a0, bB[t * 2 + 0], acc[4 + t]);
      acc[4 + t] = MFMA(a1, bB[t * 2 + 1], acc[4 + t]);
    }
    #pragma unroll
    for (int t = 0; t < 8; ++t) {
      #pragma unroll
      for (int g = 0; g < 4; ++g)
        OutS[(w * 16 + q * 4 + g) * 132 + t * 16 + r] =
            bf2f((u16)fpr[t][g]) - sc[g] * acc[t][g];
    }
    LDS_FENCE();
    #pragma unroll
    for (int jj = 0; jj < 8; ++jj) {
      f32x4 ov = *(const f32x4*)&OutS[(w * 16 + (lane >> 5) + jj * 2) * 132 + (lane & 31) * 4];
      *(f32x4*)&out[(size_t)(m0 + w * 16 + (lane >> 5) + jj * 2) * 512 + nc * 128 + (lane & 31) * 4] = ov;
    }
    LDS_FENCE();
  }
}

// ---------------------------------------------------------------------------
// K2b (fast path): pure streaming out = F - (num/denom)*GV, GV precomputed bf16.
__global__ __launch_bounds__(256, 2) void k_out2(
    const u16* __restrict__ FP, const u16* __restrict__ GVB,
    const float* __restrict__ NUM, const float* __restrict__ DP,
    float* __restrict__ out) {
  __shared__ float red[256];
  __shared__ __align__(16) float OutS[64 * 132];
  const int tid = threadIdx.x;
  const int lane = tid & 63, w = tid >> 6, q = lane >> 4, r = lane & 15;
  const int m0 = blockIdx.x * 64;
  const int strip = blockIdx.x * 4 + w;
  const int h = lane >> 5, c4 = lane & 31;
  red[tid] = DP[tid];
  __syncthreads();
  for (int s = 128; s >= 1; s >>= 1) {
    if (tid < s) red[tid] += red[tid + s];
    __syncthreads();
  }
  const float inv_denom = 1.f / red[0];
  float sc[4];
  #pragma unroll
  for (int g = 0; g < 4; ++g) sc[g] = NUM[m0 + w * 16 + q * 4 + g] * inv_denom;
  #pragma unroll 1
  for (int nc = 0; nc < 4; ++nc) {
    #pragma unroll
    for (int t = 0; t < 8; ++t) {
      size_t base = (size_t)(((strip * 4 + nc) * 8 + t) * 64 + lane) * 4;
      short4v f4 = *(const short4v*)&FP[base];
      short4v g4 = *(const short4v*)&GVB[base];
      #pragma unroll
      for (int g = 0; g < 4; ++g)
        OutS[(w * 16 + q * 4 + g) * 132 + t * 16 + r] =
            bf2f((u16)f4[g]) - sc[g] * bf2f((u16)g4[g]);
    }
    LDS_FENCE();
    #pragma unroll
    for (int jj = 0; jj < 8; ++jj) {
      f32x4 ov = *(const f32x4*)&OutS[(w * 16 + h + jj * 2) * 132 + c4 * 4];
      *(f32x4*)&out[(size_t)(m0 + w * 16 + h + jj * 2) * 512 + nc * 128 + c4 * 4] = ov;
    }
    LDS_FENCE();
  }
}

// ---------------------------------------------------------------------------
extern "C" void kernel_launch(void* const* d_in, const int* in_sizes, int n_in,
                              void* d_out, int out_size, void* d_ws, size_t ws_size,
                              hipStream_t stream) {
  const float* x  = (const float*)d_in[0];
  const float* W1 = (const float*)d_in[1];
  const float* b1 = (const float*)d_in[2];
  const float* W2 = (const float*)d_in[3];
  const float* b2 = (const float*)d_in[4];
  const float* W3 = (const float*)d_in[5];
  const float* b3 = (const float*)d_in[6];
  const float* V1 = (const float*)d_in[7];
  const float* c1 = (const float*)d_in[8];
  const float* V2 = (const float*)d_in[9];
  const float* c2 = (const float*)d_in[10];
  const float* V3 = (const float*)d_in[11];
  const float* c3 = (const float*)d_in[12];
  float* out = (float*)d_out;

  u16* FP  = (u16*)d_ws;                       // 32 MB
  u16* T2P = FP + 16777216;                    // 4 MB
  float* NUM = (float*)(T2P + 2097152);        // 32768 f
  float* DP  = NUM + 32768;                    // 256 f
  u16* PW1T = (u16*)(DP + 256);
  u16* PW1n = PW1T + 32768;
  u16* PV1T = PW1n + 32768;
  u16* PV1n = PV1T + 32768;
  u16* PW3T = PV1n + 32768;
  u16* PW3n = PW3T + 32768;
  u16* PW2T = PW3n + 32768;
  u16* PW2n = PW2T + 4096;
  u16* PV2T = PW2n + 4096;
  u16* PV2n = PV2T + 4096;
  u16* GVB_base = PV2n + 4096;                 // 32 MB if it fits
  size_t need_bytes = ((size_t)(GVB_base - (u16*)d_ws) + 16777216) * sizeof(u16);
  u16* GVB = (ws_size >= need_bytes) ? GVB_base : nullptr;

  k_conv<<<128, 256, 0, stream>>>(W1, W2, W3, V1, V2,
                                  PW1T, PW1n, PV1T, PV1n, PW3T, PW3n,
                                  PW2T, PW2n, PV2T, PV2n, DP);
  k_fused<<<512, 256, 0, stream>>>(x, PW1T, b1, PW2T, b2, PW3T, b3, PV1T, c1,
                                   PV2T, PV2n, c2, V3, c3, PV1n, PW3n, PW2n, PW1n,
                                   FP, T2P, GVB, NUM, DP);
  if (GVB != nullptr) {
    k_out2<<<512, 256, 0, stream>>>(FP, GVB, NUM, DP, out);
  } else {
    k_out<<<512, 256, 0, stream>>>(T2P, PW1n, FP, NUM, DP, out);
  }
}

// Round 9
// 175.155 us; speedup vs baseline: 1.0294x; 1.0294x over previous
//
#include <hip/hip_runtime.h>

#define ALPHA_C 0.9f
#define EPS_C 1e-3f

typedef unsigned short u16;
typedef __attribute__((ext_vector_type(8))) short short8;
typedef __attribute__((ext_vector_type(4))) short short4v;
typedef __attribute__((ext_vector_type(4))) float f32x4;
#define MFMA(a, b, c) __builtin_amdgcn_mfma_f32_16x16x32_bf16(a, b, c, 0, 0, 0)
#define LDS_FENCE() asm volatile("" ::: "memory")
// raw barriers: do NOT drain vmcnt (in-flight global loads/stores survive)
#define BAR_TOP()    { LDS_FENCE(); __builtin_amdgcn_s_barrier(); LDS_FENCE(); }
#define BAR_STAGED() { LDS_FENCE(); asm volatile("s_waitcnt lgkmcnt(0)" ::: "memory"); \
                       __builtin_amdgcn_s_barrier(); LDS_FENCE(); }

__device__ __forceinline__ u16 f2bf(float f) {
  union { float f; unsigned u; } v; v.f = f;
  unsigned u = v.u;
  u += 0x7FFFu + ((u >> 16) & 1u);
  return (u16)(u >> 16);
}
__device__ __forceinline__ float bf2f(u16 h) {
  union { unsigned u; float f; } v; v.u = ((unsigned)h) << 16;
  return v.f;
}

// ---------------------------------------------------------------------------
// K0: weight conversion fp32 -> bf16, packed in MFMA B-fragment order.
__global__ __launch_bounds__(256) void k_conv(
    const float* __restrict__ W1, const float* __restrict__ W2, const float* __restrict__ W3,
    const float* __restrict__ V1, const float* __restrict__ V2,
    u16* __restrict__ PW1T, u16* __restrict__ PW1n, u16* __restrict__ PV1T, u16* __restrict__ PV1n,
    u16* __restrict__ PW3T, u16* __restrict__ PW3n, u16* __restrict__ PW2T, u16* __restrict__ PW2n,
    u16* __restrict__ PV2T, u16* __restrict__ PV2n, float* __restrict__ DP) {
  int i = blockIdx.x * 256 + threadIdx.x;   // 0..32767
  if (i < 256) DP[i] = 0.f;
  {
    int k = i >> 6, j = i & 63;             // W1[k][j], V1[k][j]  (512x64)
    u16 b = f2bf(W1[i]);
    PW1T[((((j >> 4) * 16 + (k >> 5)) * 4 + ((k & 31) >> 3)) * 16 + (j & 15)) * 8 + (k & 7)] = b;
    PW1n[((((k >> 4) * 2 + (j >> 5)) * 4 + ((j & 31) >> 3)) * 16 + (k & 15)) * 8 + (j & 7)] = b;
    u16 c = f2bf(V1[i]);
    PV1T[((((j >> 4) * 16 + (k >> 5)) * 4 + ((k & 31) >> 3)) * 16 + (j & 15)) * 8 + (k & 7)] = c;
    PV1n[((((k >> 4) * 2 + (j >> 5)) * 4 + ((j & 31) >> 3)) * 16 + (k & 15)) * 8 + (j & 7)] = c;
  }
  {
    int k = i >> 9, n = i & 511;            // W3[k][n] (64x512)
    u16 b = f2bf(W3[i]);
    PW3T[((((n >> 4) * 2 + (k >> 5)) * 4 + ((k & 31) >> 3)) * 16 + (n & 15)) * 8 + (k & 7)] = b;
    PW3n[((((k >> 4) * 16 + (n >> 5)) * 4 + ((n & 31) >> 3)) * 16 + (k & 15)) * 8 + (n & 7)] = b;
  }
  if (i < 4096) {
    int k = i >> 6, j = i & 63;             // W2[k][j], V2[k][j] (64x64)
    u16 b = f2bf(W2[i]);
    PW2T[((((j >> 4) * 2 + (k >> 5)) * 4 + ((k & 31) >> 3)) * 16 + (j & 15)) * 8 + (k & 7)] = b;
    PW2n[((((k >> 4) * 2 + (j >> 5)) * 4 + ((j & 31) >> 3)) * 16 + (k & 15)) * 8 + (j & 7)] = b;
    u16 c = f2bf(V2[i]);
    PV2T[((((j >> 4) * 2 + (k >> 5)) * 4 + ((k & 31) >> 3)) * 16 + (j & 15)) * 8 + (k & 7)] = c;
    PV2n[((((k >> 4) * 2 + (j >> 5)) * 4 + ((j & 31) >> 3)) * 16 + (k & 15)) * 8 + (j & 7)] = c;
  }
}

// helper for k_out fallback (256 threads)
#define LDG8(dst, P, FRAG)                                                      \
  _Pragma("unroll") for (int j = 0; j < 8; ++j)                                 \
    dst[j] = *(const short8*)&P[((size_t)(FRAG) * 64 + lane) * 8];

// 512-thread staging: 16 contiguous fragments (16KB) into Ws at local frag DST
#define STAGE16B(DST, P, SRCFRAG)                                               \
  _Pragma("unroll") for (int c = 0; c < 2; ++c)                                 \
    *(short8*)&Ws[((DST) * 512) + (c * 512 + tid) * 8] =                        \
      *(const short8*)&P[((size_t)(SRCFRAG) * 512) + (c * 512 + tid) * 8];

// 512-thread staging: 4 chunks of 4 frags: local (DST+t*4..+3) <- global (t*16+OFF..)
#define STAGE4x4B(DST, P, OFF)                                                  \
  _Pragma("unroll") for (int c = 0; c < 2; ++c) {                               \
    int t_ = c * 2 + (tid >> 8);                                                \
    *(short8*)&Ws[((DST) + t_ * 4) * 512 + (tid & 255) * 8] =                   \
      *(const short8*)&P[((size_t)(t_ * 16 + (OFF))) * 512 + (tid & 255) * 8];  \
  }

// ---------------------------------------------------------------------------
// 512 threads = 8 waves: 4 row strips (ws) x 2 column halves (wh).
__global__ __launch_bounds__(512, 4) void k_fused(
    const float* __restrict__ x,
    const u16* __restrict__ PW1T, const float* __restrict__ b1,
    const u16* __restrict__ PW2T, const float* __restrict__ b2,
    const u16* __restrict__ PW3T, const float* __restrict__ b3,
    const u16* __restrict__ PV1T, const float* __restrict__ c1,
    const u16* __restrict__ PV2T, const u16* __restrict__ PV2n, const float* __restrict__ c2,
    const float* __restrict__ V3, const float* __restrict__ c3,
    const u16* __restrict__ PV1n, const u16* __restrict__ PW3n,
    const u16* __restrict__ PW2n, const u16* __restrict__ PW1n,
    u16* __restrict__ FP, u16* __restrict__ T2P, u16* __restrict__ GVB,
    float* __restrict__ NUM, float* __restrict__ DP) {
  __shared__ __align__(16) u16 H1s[64 * 72];
  __shared__ __align__(16) u16 H2s[64 * 72];
  __shared__ __align__(16) u16 S2s[64 * 72];
  __shared__ __align__(16) u16 As[64 * 136];   // also aliased as pair-reduce scratch
  __shared__ __align__(16) u16 Ws[16384];      // 32 KB shared weight window
  __shared__ float dred[4];
  const int tid = threadIdx.x;
  const int lane = tid & 63, w = tid >> 6, q = lane >> 4, r = lane & 15;
  const int ws = w & 3, wh = w >> 2;           // row strip / column half
  const int m0 = blockIdx.x * 64;
  const int arow = ws * 16 + r;
  const int strip = blockIdx.x * 4 + ws;
  float* xf = (float*)As;                      // pair-reduction scratch alias

  // ================= phase A1: H1 = relu(x @ W1 + b1) =================
  f32x4 acc1[2] = {};
  {
    const int L = (wh << 6) | lane, h4 = L >> 5, cc = L & 31;
    const float* xb = x + (size_t)(m0 + ws * 16) * 512;
    float4 xr[4];
    #pragma unroll
    for (int it = 0; it < 4; ++it)
      xr[it] = *(const float4*)&xb[(it * 4 + h4) * 512 + cc * 4];
    #pragma unroll 1
    for (int kc = 0; kc < 4; ++kc) {
      BAR_TOP();
      STAGE4x4B(0, PW1T, kc * 4);
      #pragma unroll
      for (int it = 0; it < 4; ++it) {
        float4 v = xr[it]; short4v s4;
        s4[0] = (short)f2bf(v.x); s4[1] = (short)f2bf(v.y);
        s4[2] = (short)f2bf(v.z); s4[3] = (short)f2bf(v.w);
        *(short4v*)&As[(ws * 16 + it * 4 + h4) * 136 + cc * 4] = s4;
      }
      if (kc < 3) {
        #pragma unroll
        for (int it = 0; it < 4; ++it)
          xr[it] = *(const float4*)&xb[(it * 4 + h4) * 512 + (kc + 1) * 128 + cc * 4];
      }
      BAR_STAGED();
      #pragma unroll
      for (int ks = 0; ks < 4; ++ks) {
        short8 a = *(const short8*)&As[arow * 136 + ks * 32 + q * 8];
        #pragma unroll
        for (int tt = 0; tt < 2; ++tt) {
          short8 b = *(const short8*)&Ws[(((wh * 2 + tt) * 4 + ks) * 64 + lane) * 8];
          acc1[tt] = MFMA(a, b, acc1[tt]);
        }
      }
    }
  }
  #pragma unroll
  for (int tt = 0; tt < 2; ++tt) {
    int col = (wh * 2 + tt) * 16 + r; float bv = b1[col];
    #pragma unroll
    for (int g = 0; g < 4; ++g) {
      float hh = acc1[tt][g] + bv; hh = hh > 0.f ? hh : 0.f;
      H1s[(ws * 16 + q * 4 + g) * 72 + col] = f2bf(hh);
    }
  }
  BAR_STAGED();

  // ================= phase A2: H2 = relu(H1 @ W2 + b2) =================
  {
    short8 a0 = *(const short8*)&H1s[arow * 72 + 0 + q * 8];
    short8 a1 = *(const short8*)&H1s[arow * 72 + 32 + q * 8];
    f32x4 acc2[2] = {};
    #pragma unroll
    for (int tt = 0; tt < 2; ++tt) {
      int t = wh * 2 + tt;
      short8 b0 = *(const short8*)&PW2T[((t * 2 + 0) * 64 + lane) * 8];
      short8 b1 = *(const short8*)&PW2T[((t * 2 + 1) * 64 + lane) * 8];
      acc2[tt] = MFMA(a0, b0, acc2[tt]);
      acc2[tt] = MFMA(a1, b1, acc2[tt]);
    }
    #pragma unroll
    for (int tt = 0; tt < 2; ++tt) {
      int col = (wh * 2 + tt) * 16 + r; float bv = b2[col];
      #pragma unroll
      for (int g = 0; g < 4; ++g) {
        float hh = acc2[tt][g] + bv; hh = hh > 0.f ? hh : 0.f;
        H2s[(ws * 16 + q * 4 + g) * 72 + col] = f2bf(hh);
      }
    }
  }
  BAR_STAGED();
  short8 h2a0 = *(const short8*)&H2s[arow * 72 + 0 + q * 8];
  short8 h2a1 = *(const short8*)&H2s[arow * 72 + 32 + q * 8];

  // ================= phase B: F = H2 @ W3 + b3; G1 accum = F @ V1 =================
  f32x4 g1acc[2] = {};
  float ssqp[4] = {0.f, 0.f, 0.f, 0.f};
  #pragma unroll 1
  for (int nc = 0; nc < 4; ++nc) {
    BAR_TOP();
    STAGE16B(0, PW3T, nc * 16);
    STAGE4x4B(16, PV1T, nc * 4);
    BAR_STAGED();
    f32x4 facc[4] = {};
    #pragma unroll
    for (int tt = 0; tt < 4; ++tt) {
      int t = wh * 4 + tt;
      short8 b0 = *(const short8*)&Ws[((t * 2 + 0) * 64 + lane) * 8];
      short8 b1 = *(const short8*)&Ws[((t * 2 + 1) * 64 + lane) * 8];
      facc[tt] = MFMA(h2a0, b0, facc[tt]);
      facc[tt] = MFMA(h2a1, b1, facc[tt]);
    }
    #pragma unroll
    for (int tt = 0; tt < 4; ++tt) {
      int t = wh * 4 + tt;
      float bv = b3[nc * 128 + t * 16 + r];
      short4v s4;
      #pragma unroll
      for (int g = 0; g < 4; ++g) {
        float v = facc[tt][g] + bv;
        ssqp[g] += v * v;
        u16 bb = f2bf(v);
        As[(ws * 16 + q * 4 + g) * 136 + t * 16 + r] = bb;
        s4[g] = (short)bb;
      }
      *(short4v*)&FP[(size_t)(((strip * 4 + nc) * 8 + t) * 64 + lane) * 4] = s4;
    }
    BAR_STAGED();
    #pragma unroll
    for (int ks = 0; ks < 4; ++ks) {
      short8 a = *(const short8*)&As[arow * 136 + ks * 32 + q * 8];
      #pragma unroll
      for (int tt = 0; tt < 2; ++tt) {
        int t = wh * 2 + tt;
        short8 b = *(const short8*)&Ws[((16 + t * 4 + ks) * 64 + lane) * 8];
        g1acc[tt] = MFMA(a, b, g1acc[tt]);
      }
    }
  }

  // G1 = relu(g1acc + c1) -> S2s
  f32x4 g1v[2];
  #pragma unroll
  for (int tt = 0; tt < 2; ++tt) {
    int col = (wh * 2 + tt) * 16 + r; float cv = c1[col];
    #pragma unroll
    for (int g = 0; g < 4; ++g) {
      float v = g1acc[tt][g] + cv; v = v > 0.f ? v : 0.f;
      g1v[tt][g] = v;
      S2s[(ws * 16 + q * 4 + g) * 72 + col] = f2bf(v);
    }
  }
  BAR_STAGED();
  // g2 = G1 @ V2T
  f32x4 g2acc[2] = {};
  {
    short8 a0 = *(const short8*)&S2s[arow * 72 + 0 + q * 8];
    short8 a1 = *(const short8*)&S2s[arow * 72 + 32 + q * 8];
    #pragma unroll
    for (int tt = 0; tt < 2; ++tt) {
      int t = wh * 2 + tt;
      short8 b0 = *(const short8*)&PV2T[((t * 2 + 0) * 64 + lane) * 8];
      short8 b1 = *(const short8*)&PV2T[((t * 2 + 1) * 64 + lane) * 8];
      g2acc[tt] = MFMA(a0, b0, g2acc[tt]);
      g2acc[tt] = MFMA(a1, b1, g2acc[tt]);
    }
  }
  // s3 = (g2pre>0)*V3 -> S2s; lyap partial (cols of this half)
  float totp[4] = {0.f, 0.f, 0.f, 0.f};
  #pragma unroll
  for (int tt = 0; tt < 2; ++tt) {
    int col = (wh * 2 + tt) * 16 + r;
    float c2v = c2[col], v3v = V3[col];
    #pragma unroll
    for (int g = 0; g < 4; ++g) {
      float pre = g2acc[tt][g] + c2v;
      float g2 = pre > 0.f ? pre : 0.f;
      S2s[(ws * 16 + q * 4 + g) * 72 + col] = pre > 0.f ? f2bf(v3v) : (u16)0;
      totp[g] += g2 * v3v;
    }
  }
  BAR_STAGED();
  // s2 = s3 @ V2 (natural), masked by G1>0 -> S2s
  f32x4 s2acc[2] = {};
  {
    short8 a0 = *(const short8*)&S2s[arow * 72 + 0 + q * 8];
    short8 a1 = *(const short8*)&S2s[arow * 72 + 32 + q * 8];
    #pragma unroll
    for (int tt = 0; tt < 2; ++tt) {
      int t = wh * 2 + tt;
      short8 b0 = *(const short8*)&PV2n[((t * 2 + 0) * 64 + lane) * 8];
      short8 b1 = *(const short8*)&PV2n[((t * 2 + 1) * 64 + lane) * 8];
      s2acc[tt] = MFMA(a0, b0, s2acc[tt]);
      s2acc[tt] = MFMA(a1, b1, s2acc[tt]);
    }
  }
  #pragma unroll
  for (int tt = 0; tt < 2; ++tt) {
    int col = (wh * 2 + tt) * 16 + r;
    #pragma unroll
    for (int g = 0; g < 4; ++g) {
      float sv = g1v[tt][g] > 0.f ? s2acc[tt][g] : 0.f;
      S2s[(ws * 16 + q * 4 + g) * 72 + col] = f2bf(sv);
    }
  }
  BAR_STAGED();
  // lyap: pair-reduce (totp + eps*ssqp) across column halves via xf (As alias)
  #pragma unroll
  for (int g = 0; g < 4; ++g) {
    float s = totp[g] + EPS_C * ssqp[g];
    s += __shfl_xor(s, 1); s += __shfl_xor(s, 2); s += __shfl_xor(s, 4); s += __shfl_xor(s, 8);
    if (r == 0) xf[w * 16 + q * 4 + g] = s;
  }
  BAR_STAGED();
  float c3v = c3[0];
  float lyap_row[4];
  #pragma unroll
  for (int g = 0; g < 4; ++g)
    lyap_row[g] = xf[w * 16 + q * 4 + g] + xf[(w ^ 4) * 16 + q * 4 + g] + c3v;

  // all FP stores must land before same-address re-reads in phase C
  asm volatile("s_waitcnt vmcnt(0)" ::: "memory");

  // ================= phase C: U = s2 @ V1^T + 2eps*F; T3 accum = U @ W3^T =================
  f32x4 t3acc[2] = {};
  short8 s2a0 = *(const short8*)&S2s[arow * 72 + 0 + q * 8];
  short8 s2a1 = *(const short8*)&S2s[arow * 72 + 32 + q * 8];
  #pragma unroll 1
  for (int nc = 0; nc < 4; ++nc) {
    BAR_TOP();
    STAGE16B(0, PV1n, nc * 16);
    STAGE4x4B(16, PW3n, nc * 4);
    BAR_STAGED();
    short4v fpr[4];
    #pragma unroll
    for (int tt = 0; tt < 4; ++tt)
      fpr[tt] = *(const short4v*)&FP[(size_t)(((strip * 4 + nc) * 8 + wh * 4 + tt) * 64 + lane) * 4];
    f32x4 uacc[4] = {};
    #pragma unroll
    for (int tt = 0; tt < 4; ++tt) {
      int t = wh * 4 + tt;
      short8 b0 = *(const short8*)&Ws[((t * 2 + 0) * 64 + lane) * 8];
      short8 b1 = *(const short8*)&Ws[((t * 2 + 1) * 64 + lane) * 8];
      uacc[tt] = MFMA(s2a0, b0, uacc[tt]);
      uacc[tt] = MFMA(s2a1, b1, uacc[tt]);
    }
    #pragma unroll
    for (int tt = 0; tt < 4; ++tt) {
      int t = wh * 4 + tt;
      #pragma unroll
      for (int g = 0; g < 4; ++g) {
        As[(ws * 16 + q * 4 + g) * 136 + t * 16 + r] =
            f2bf(uacc[tt][g] + 2.f * EPS_C * bf2f((u16)fpr[tt][g]));
      }
    }
    BAR_STAGED();
    #pragma unroll
    for (int ks = 0; ks < 4; ++ks) {
      short8 a = *(const short8*)&As[arow * 136 + ks * 32 + q * 8];
      #pragma unroll
      for (int tt = 0; tt < 2; ++tt) {
        int t = wh * 2 + tt;
        short8 b = *(const short8*)&Ws[((16 + t * 4 + ks) * 64 + lane) * 8];
        t3acc[tt] = MFMA(a, b, t3acc[tt]);
      }
    }
  }
  // T3 masked by H2>0 -> H2s (own cols)
  #pragma unroll
  for (int tt = 0; tt < 2; ++tt) {
    int col = (wh * 2 + tt) * 16 + r;
    #pragma unroll
    for (int g = 0; g < 4; ++g) {
      int addr = (ws * 16 + q * 4 + g) * 72 + col;
      u16 h2 = H2s[addr];
      H2s[addr] = h2 ? f2bf(t3acc[tt][g]) : (u16)0;
    }
  }
  BAR_STAGED();
  // T2 = T3 @ W2 (natural), masked by H1>0 -> H1s (own cols)
  f32x4 t2acc[2] = {};
  {
    short8 a0 = *(const short8*)&H2s[arow * 72 + 0 + q * 8];
    short8 a1 = *(const short8*)&H2s[arow * 72 + 32 + q * 8];
    #pragma unroll
    for (int tt = 0; tt < 2; ++tt) {
      int t = wh * 2 + tt;
      short8 b0 = *(const short8*)&PW2n[((t * 2 + 0) * 64 + lane) * 8];
      short8 b1 = *(const short8*)&PW2n[((t * 2 + 1) * 64 + lane) * 8];
      t2acc[tt] = MFMA(a0, b0, t2acc[tt]);
      t2acc[tt] = MFMA(a1, b1, t2acc[tt]);
    }
  }
  #pragma unroll
  for (int tt = 0; tt < 2; ++tt) {
    int col = (wh * 2 + tt) * 16 + r;
    #pragma unroll
    for (int g = 0; g < 4; ++g) {
      int addr = (ws * 16 + q * 4 + g) * 72 + col;
      u16 h1 = H1s[addr];
      H1s[addr] = h1 ? f2bf(t2acc[tt][g]) : (u16)0;
    }
  }
  BAR_STAGED();
  // T2 full-row A-fragments; packed store split across halves
  short8 v0 = *(const short8*)&H1s[arow * 72 + 0 + q * 8];
  short8 v1 = *(const short8*)&H1s[arow * 72 + 32 + q * 8];
  if (wh == 0) *(short8*)&T2P[(size_t)((strip * 2 + 0) * 64 + lane) * 8] = v0;
  else         *(short8*)&T2P[(size_t)((strip * 2 + 1) * 64 + lane) * 8] = v1;

  // ============ GV = T2 @ W1^T: row norms + packed bf16 GV store ============
  float ssq2p[4] = {0.f, 0.f, 0.f, 0.f};
  #pragma unroll 1
  for (int nc = 0; nc < 4; ++nc) {
    BAR_TOP();
    STAGE16B(0, PW1n, nc * 16);
    BAR_STAGED();
    #pragma unroll
    for (int tt = 0; tt < 4; ++tt) {
      int t = wh * 4 + tt;
      short8 b0 = *(const short8*)&Ws[((t * 2 + 0) * 64 + lane) * 8];
      short8 b1 = *(const short8*)&Ws[((t * 2 + 1) * 64 + lane) * 8];
      f32x4 a = {};
      a = MFMA(v0, b0, a);
      a = MFMA(v1, b1, a);
      short4v s4;
      #pragma unroll
      for (int g = 0; g < 4; ++g) {
        ssq2p[g] += a[g] * a[g];
        s4[g] = (short)f2bf(a[g]);
      }
      if (GVB != nullptr)
        *(short4v*)&GVB[(size_t)(((strip * 4 + nc) * 8 + t) * 64 + lane) * 4] = s4;
    }
  }
  // pair-reduce ssq2p, write NUM, block partial -> DP
  #pragma unroll
  for (int g = 0; g < 4; ++g) {
    float s = ssq2p[g];
    s += __shfl_xor(s, 1); s += __shfl_xor(s, 2); s += __shfl_xor(s, 4); s += __shfl_xor(s, 8);
    if (r == 0) xf[w * 16 + q * 4 + g] = s;
  }
  BAR_STAGED();
  float totw = 0.f;
  #pragma unroll
  for (int g = 0; g < 4; ++g) {
    float s = xf[w * 16 + q * 4 + g] + xf[(w ^ 4) * 16 + q * 4 + g];
    if (r == 0 && wh == 0) {
      int rowg = m0 + ws * 16 + q * 4 + g;
      float nm = s + ALPHA_C * lyap_row[g];
      NUM[rowg] = nm > 0.f ? nm : 0.f;
    }
    s += __shfl_xor(s, 16); s += __shfl_xor(s, 32);
    totw += s;
  }
  if (lane == 0 && wh == 0) dred[ws] = totw;
  __syncthreads();
  if (tid == 0) atomicAdd(&DP[blockIdx.x & 255], dred[0] + dred[1] + dred[2] + dred[3]);
}

// ---------------------------------------------------------------------------
// K2a (fallback): recompute GV from packed T2 via MFMA; out = F - (num/denom)*GV.
__global__ __launch_bounds__(256, 2) void k_out(
    const u16* __restrict__ T2P, const u16* __restrict__ PW1n,
    const u16* __restrict__ FP, const float* __restrict__ NUM, const float* __restrict__ DP,
    float* __restrict__ out) {
  __shared__ float red[256];
  __shared__ __align__(16) float OutS[64 * 132];
  const int tid = threadIdx.x;
  const int lane = tid & 63, w = tid >> 6, q = lane >> 4, r = lane & 15;
  const int m0 = blockIdx.x * 64;
  const int strip = blockIdx.x * 4 + w;
  red[tid] = DP[tid];
  __syncthreads();
  for (int s = 128; s >= 1; s >>= 1) {
    if (tid < s) red[tid] += red[tid + s];
    __syncthreads();
  }
  const float inv_denom = 1.f / red[0];
  float sc[4];
  #pragma unroll
  for (int g = 0; g < 4; ++g) sc[g] = NUM[m0 + w * 16 + q * 4 + g] * inv_denom;
  short8 a0 = *(const short8*)&T2P[(size_t)((strip * 2 + 0) * 64 + lane) * 8];
  short8 a1 = *(const short8*)&T2P[(size_t)((strip * 2 + 1) * 64 + lane) * 8];
  short8 bA[8], bB[8];
  LDG8(bA, PW1n, ((j >> 1) * 2 + (j & 1)));
  #pragma unroll 1
  for (int nc = 0; nc < 4; ++nc) {
    LDG8(bB, PW1n, ((nc * 8 + 4 + (j >> 1)) * 2 + (j & 1)));
    short4v fpr[8];
    #pragma unroll
    for (int t = 0; t < 8; ++t)
      fpr[t] = *(const short4v*)&FP[(size_t)(((strip * 4 + nc) * 8 + t) * 64 + lane) * 4];
    f32x4 acc[8] = {};
    #pragma unroll
    for (int t = 0; t < 4; ++t) {
      acc[t] = MFMA(a0, bA[t * 2 + 0], acc[t]);
      acc[t] = MFMA(a1, bA[t * 2 + 1], acc[t]);
    }
    int ncn = (nc + 1) & 3;
    LDG8(bA, PW1n, ((ncn * 8 + (j >> 1)) * 2 + (j & 1)));
    #pragma unroll
    for (int t = 0; t < 4; ++t) {
      acc[4 + t] = MFMA(a0, bB[t * 2 + 0], acc[4 + t]);
      acc[4 + t] = MFMA(a1, bB[t * 2 + 1], acc[4 + t]);
    }
    #pragma unroll
    for (int t = 0; t < 8; ++t) {
      #pragma unroll
      for (int g = 0; g < 4; ++g)
        OutS[(w * 16 + q * 4 + g) * 132 + t * 16 + r] =
            bf2f((u16)fpr[t][g]) - sc[g] * acc[t][g];
    }
    LDS_FENCE();
    #pragma unroll
    for (int jj = 0; jj < 8; ++jj) {
      f32x4 ov = *(const f32x4*)&OutS[(w * 16 + (lane >> 5) + jj * 2) * 132 + (lane & 31) * 4];
      *(f32x4*)&out[(size_t)(m0 + w * 16 + (lane >> 5) + jj * 2) * 512 + nc * 128 + (lane & 31) * 4] = ov;
    }
    LDS_FENCE();
  }
}

// ---------------------------------------------------------------------------
// K2b (fast path): pure streaming out = F - (num/denom)*GV, GV precomputed bf16.
__global__ __launch_bounds__(256, 2) void k_out2(
    const u16* __restrict__ FP, const u16* __restrict__ GVB,
    const float* __restrict__ NUM, const float* __restrict__ DP,
    float* __restrict__ out) {
  __shared__ float red[256];
  __shared__ __align__(16) float OutS[64 * 132];
  const int tid = threadIdx.x;
  const int lane = tid & 63, w = tid >> 6, q = lane >> 4, r = lane & 15;
  const int m0 = blockIdx.x * 64;
  const int strip = blockIdx.x * 4 + w;
  const int h = lane >> 5, c4 = lane & 31;
  red[tid] = DP[tid];
  __syncthreads();
  for (int s = 128; s >= 1; s >>= 1) {
    if (tid < s) red[tid] += red[tid + s];
    __syncthreads();
  }
  const float inv_denom = 1.f / red[0];
  float sc[4];
  #pragma unroll
  for (int g = 0; g < 4; ++g) sc[g] = NUM[m0 + w * 16 + q * 4 + g] * inv_denom;
  #pragma unroll 1
  for (int nc = 0; nc < 4; ++nc) {
    #pragma unroll
    for (int t = 0; t < 8; ++t) {
      size_t base = (size_t)(((strip * 4 + nc) * 8 + t) * 64 + lane) * 4;
      short4v f4 = *(const short4v*)&FP[base];
      short4v g4 = *(const short4v*)&GVB[base];
      #pragma unroll
      for (int g = 0; g < 4; ++g)
        OutS[(w * 16 + q * 4 + g) * 132 + t * 16 + r] =
            bf2f((u16)f4[g]) - sc[g] * bf2f((u16)g4[g]);
    }
    LDS_FENCE();
    #pragma unroll
    for (int jj = 0; jj < 8; ++jj) {
      f32x4 ov = *(const f32x4*)&OutS[(w * 16 + h + jj * 2) * 132 + c4 * 4];
      *(f32x4*)&out[(size_t)(m0 + w * 16 + h + jj * 2) * 512 + nc * 128 + c4 * 4] = ov;
    }
    LDS_FENCE();
  }
}

// ---------------------------------------------------------------------------
extern "C" void kernel_launch(void* const* d_in, const int* in_sizes, int n_in,
                              void* d_out, int out_size, void* d_ws, size_t ws_size,
                              hipStream_t stream) {
  const float* x  = (const float*)d_in[0];
  const float* W1 = (const float*)d_in[1];
  const float* b1 = (const float*)d_in[2];
  const float* W2 = (const float*)d_in[3];
  const float* b2 = (const float*)d_in[4];
  const float* W3 = (const float*)d_in[5];
  const float* b3 = (const float*)d_in[6];
  const float* V1 = (const float*)d_in[7];
  const float* c1 = (const float*)d_in[8];
  const float* V2 = (const float*)d_in[9];
  const float* c2 = (const float*)d_in[10];
  const float* V3 = (const float*)d_in[11];
  const float* c3 = (const float*)d_in[12];
  float* out = (float*)d_out;

  u16* FP  = (u16*)d_ws;                       // 32 MB
  u16* T2P = FP + 16777216;                    // 4 MB
  float* NUM = (float*)(T2P + 2097152);        // 32768 f
  float* DP  = NUM + 32768;                    // 256 f
  u16* PW1T = (u16*)(DP + 256);
  u16* PW1n = PW1T + 32768;
  u16* PV1T = PW1n + 32768;
  u16* PV1n = PV1T + 32768;
  u16* PW3T = PV1n + 32768;
  u16* PW3n = PW3T + 32768;
  u16* PW2T = PW3n + 32768;
  u16* PW2n = PW2T + 4096;
  u16* PV2T = PW2n + 4096;
  u16* PV2n = PV2T + 4096;
  u16* GVB_base = PV2n + 4096;                 // 32 MB if it fits
  size_t need_bytes = ((size_t)(GVB_base - (u16*)d_ws) + 16777216) * sizeof(u16);
  u16* GVB = (ws_size >= need_bytes) ? GVB_base : nullptr;

  k_conv<<<128, 256, 0, stream>>>(W1, W2, W3, V1, V2,
                                  PW1T, PW1n, PV1T, PV1n, PW3T, PW3n,
                                  PW2T, PW2n, PV2T, PV2n, DP);
  k_fused<<<512, 512, 0, stream>>>(x, PW1T, b1, PW2T, b2, PW3T, b3, PV1T, c1,
                                   PV2T, PV2n, c2, V3, c3, PV1n, PW3n, PW2n, PW1n,
                                   FP, T2P, GVB, NUM, DP);
  if (GVB != nullptr) {
    k_out2<<<512, 256, 0, stream>>>(FP, GVB, NUM, DP, out);
  } else {
    k_out<<<512, 256, 0, stream>>>(T2P, PW1n, FP, NUM, DP, out);
  }
}